// Round 1
// baseline (878.352 us; speedup 1.0000x reference)
//
#include <hip/hip_runtime.h>
#include <math.h>

#define N_NODES 16384
#define N_EDGES 524288
#define F_IN 128
#define H1 256
#define H2 256
#define D1 64

// ---------------- CSR build ----------------

__global__ void hist_kernel(const int* __restrict__ dst, int* __restrict__ indeg) {
    int e = blockIdx.x * 256 + threadIdx.x;
    if (e < N_EDGES) atomicAdd(&indeg[dst[e]], 1);
}

// single block, 256 threads; N=16384 -> 64 per thread
__global__ void scan_kernel(const int* __restrict__ indeg, int* __restrict__ rowptr,
                            int* __restrict__ cursor, float* __restrict__ dinv) {
    __shared__ int part[256];
    int t = threadIdx.x;
    int base = t * 64;
    int s = 0;
    for (int i = 0; i < 64; ++i) s += indeg[base + i];
    part[t] = s;
    __syncthreads();
    for (int off = 1; off < 256; off <<= 1) {
        int v = part[t];
        int add = (t >= off) ? part[t - off] : 0;
        __syncthreads();
        part[t] = v + add;
        __syncthreads();
    }
    int run = (t == 0) ? 0 : part[t - 1];
    for (int i = 0; i < 64; ++i) {
        int d = indeg[base + i];
        rowptr[base + i] = run;
        cursor[base + i] = run;
        dinv[base + i] = rsqrtf((float)(d + 1));   // +1 self loop; deg>=1 always
        run += d;
    }
    if (t == 255) rowptr[N_NODES] = run;
}

__global__ void fill_kernel(const int* __restrict__ src, const int* __restrict__ dst,
                            int* __restrict__ cursor, int* __restrict__ col) {
    int e = blockIdx.x * 256 + threadIdx.x;
    if (e < N_EDGES) {
        int d = dst[e];
        int p = atomicAdd(&cursor[d], 1);
        col[p] = src[e];
    }
}

// ---------------- SGEMM with row-scale epilogue ----------------
// C[i][j] = (sum_k A[i][k]*B[k][j]) * (rowscale ? rowscale[i] : 1)
template <int BM, int BN, int BK, int TM, int TN>
__global__ __launch_bounds__(256) void sgemm_rowscale(
    const float* __restrict__ A, const float* __restrict__ B,
    const float* __restrict__ rowscale, float* __restrict__ C,
    int M, int N, int K) {
    __shared__ float As[BK][BM];
    __shared__ float Bs[BK][BN];
    const int tid = threadIdx.x;
    const int tx = tid % (BN / TN);
    const int ty = tid / (BN / TN);
    const int row0 = blockIdx.y * BM;
    const int col0 = blockIdx.x * BN;
    float acc[TM][TN] = {};
    for (int k0 = 0; k0 < K; k0 += BK) {
        __syncthreads();
        #pragma unroll
        for (int i = tid; i < BM * BK; i += 256) {
            int r = i / BK, c = i % BK;
            As[c][r] = A[(size_t)(row0 + r) * K + k0 + c];
        }
        #pragma unroll
        for (int i = tid; i < BK * BN; i += 256) {
            int r = i / BN, c = i % BN;
            Bs[r][c] = B[(size_t)(k0 + r) * N + col0 + c];
        }
        __syncthreads();
        #pragma unroll
        for (int k = 0; k < BK; ++k) {
            float a[TM], b[TN];
            #pragma unroll
            for (int i = 0; i < TM; i += 4) {
                float4 v = *(const float4*)&As[k][ty * TM + i];
                a[i] = v.x; a[i + 1] = v.y; a[i + 2] = v.z; a[i + 3] = v.w;
            }
            #pragma unroll
            for (int j = 0; j < TN; j += 4) {
                float4 v = *(const float4*)&Bs[k][tx * TN + j];
                b[j] = v.x; b[j + 1] = v.y; b[j + 2] = v.z; b[j + 3] = v.w;
            }
            #pragma unroll
            for (int i = 0; i < TM; ++i)
                #pragma unroll
                for (int j = 0; j < TN; ++j)
                    acc[i][j] += a[i] * b[j];
        }
    }
    #pragma unroll
    for (int i = 0; i < TM; ++i) {
        float rs = rowscale ? rowscale[row0 + ty * TM + i] : 1.0f;
        #pragma unroll
        for (int j = 0; j < TN; j += 4) {
            float4 v;
            v.x = acc[i][j + 0] * rs;
            v.y = acc[i][j + 1] * rs;
            v.z = acc[i][j + 2] * rs;
            v.w = acc[i][j + 3] * rs;
            *(float4*)&C[(size_t)(row0 + ty * TM + i) * N + col0 + tx * TN + j] = v;
        }
    }
}

// ---------------- neighborhood aggregation ----------------
// out[d][f] = dinv[d] * (y[d][f] + sum_{s in nbr(d)} y[s][f]) + bias[f]; optional relu
__global__ __launch_bounds__(256) void aggregate_kernel(
    const float* __restrict__ y, const int* __restrict__ rowptr,
    const int* __restrict__ col, const float* __restrict__ dinv,
    const float* __restrict__ bias, float* __restrict__ out, int do_relu) {
    __shared__ int nb[256];
    int d = blockIdx.x;
    int f = threadIdx.x;
    int s0 = rowptr[d], s1 = rowptr[d + 1];
    float acc = y[(size_t)d * 256 + f];
    for (int base = s0; base < s1; base += 256) {
        int m = min(256, s1 - base);
        if (threadIdx.x < m) nb[threadIdx.x] = col[base + threadIdx.x];
        __syncthreads();
        for (int i = 0; i < m; ++i) acc += y[(size_t)nb[i] * 256 + f];
        __syncthreads();
    }
    float v = acc * dinv[d] + bias[f];
    if (do_relu) v = fmaxf(v, 0.0f);
    out[(size_t)d * 256 + f] = v;
}

// ---------------- small glue kernels ----------------

__global__ void transpose_fc1(const float* __restrict__ fc1_w, float* __restrict__ fc1t) {
    int i = blockIdx.x * 256 + threadIdx.x;   // 16384 = 256*64
    int k = i / 64, o = i % 64;
    fc1t[i] = fc1_w[o * 256 + k];             // fc1t[k][o] = fc1_w[o][k]
}

// tanh + 2-logit + softmax per node; one wave (64 threads) per node
__global__ __launch_bounds__(64) void assign_kernel(
    const float* __restrict__ a1pre, const float* __restrict__ fc1_b,
    const float* __restrict__ fc2_w, const float* __restrict__ fc2_b,
    float* __restrict__ assign) {
    int n = blockIdx.x, t = threadIdx.x;
    float a = tanhf(a1pre[(size_t)n * 64 + t] + fc1_b[t]);
    float p0 = a * fc2_w[t];
    float p1 = a * fc2_w[64 + t];
    #pragma unroll
    for (int off = 32; off; off >>= 1) {
        p0 += __shfl_down(p0, off);
        p1 += __shfl_down(p1, off);
    }
    if (t == 0) {
        p0 += fc2_b[0];
        p1 += fc2_b[1];
        float m = fmaxf(p0, p1);
        float e0 = expf(p0 - m), e1 = expf(p1 - m);
        float inv = 1.0f / (e0 + e1);
        assign[n * 2 + 0] = e0 * inv;
        assign[n * 2 + 1] = e1 * inv;
    }
}

// gf[k][f] = sum_n assign[n][k] * h2[n][f];  64 blocks of 256 nodes each
__global__ __launch_bounds__(256) void group_feat_kernel(
    const float* __restrict__ h2, const float* __restrict__ assign,
    float* __restrict__ gf) {
    __shared__ float as0[256], as1[256];
    int f = threadIdx.x;
    int n0 = blockIdx.x * 256;
    as0[f] = assign[(n0 + f) * 2 + 0];
    as1[f] = assign[(n0 + f) * 2 + 1];
    __syncthreads();
    float acc0 = 0.f, acc1 = 0.f;
    for (int i = 0; i < 256; ++i) {
        float h = h2[(size_t)(n0 + i) * 256 + f];
        acc0 += as0[i] * h;
        acc1 += as1[i] * h;
    }
    atomicAdd(&gf[f], acc0);
    atomicAdd(&gf[256 + f], acc1);
}

// new_adj[k][l] = sum_e assign[src_e][k]*assign[dst_e][l]  (dense adj never materialized)
__global__ __launch_bounds__(256) void newadj_kernel(
    const int* __restrict__ src, const int* __restrict__ dst,
    const float* __restrict__ assign, float* __restrict__ newadj) {
    int e = blockIdx.x * 256 + threadIdx.x;
    float a00 = 0.f, a01 = 0.f, a10 = 0.f, a11 = 0.f;
    if (e < N_EDGES) {
        int s = src[e], d = dst[e];
        float s0 = assign[s * 2], s1 = assign[s * 2 + 1];
        float d0 = assign[d * 2], d1 = assign[d * 2 + 1];
        a00 = s0 * d0; a01 = s0 * d1; a10 = s1 * d0; a11 = s1 * d1;
    }
    #pragma unroll
    for (int off = 32; off; off >>= 1) {
        a00 += __shfl_down(a00, off);
        a01 += __shfl_down(a01, off);
        a10 += __shfl_down(a10, off);
        a11 += __shfl_down(a11, off);
    }
    if ((threadIdx.x & 63) == 0) {
        atomicAdd(&newadj[0], a00);
        atomicAdd(&newadj[1], a01);
        atomicAdd(&newadj[2], a10);
        atomicAdd(&newadj[3], a11);
    }
}

__global__ __launch_bounds__(256) void finalize_kernel(
    const float* __restrict__ gf, const float* __restrict__ newadj,
    float* __restrict__ out) {
    int t = threadIdx.x;
    float g0 = gf[t], g1 = gf[256 + t];
    out[t] = 0.5f * (g0 + g1);                                   // graph_embedding
    out[256 + t] = fminf(fmaxf(g0, -100.f), 100.f);              // positive
    out[512 + t] = fminf(fmaxf(g1, -100.f), 100.f);              // negative
    if (t == 0) {
        float n00 = newadj[0], n01 = newadj[1], n10 = newadj[2], n11 = newadj[3];
        float den0 = fmaxf(fabsf(n00) + fabsf(n01), 1e-12f);
        float den1 = fmaxf(fabsf(n10) + fabsf(n11), 1e-12f);
        float x0 = n00 / den0 - 1.0f;
        float x1 = n11 / den1 - 1.0f;
        out[768] = 0.5f * (x0 * x0 + x1 * x1);                   // pos_penalty
    }
}

// ---------------- launch ----------------

extern "C" void kernel_launch(void* const* d_in, const int* in_sizes, int n_in,
                              void* d_out, int out_size, void* d_ws, size_t ws_size,
                              hipStream_t stream) {
    const float* features = (const float*)d_in[0];
    const int* edges = (const int*)d_in[1];
    const int* src = edges;
    const int* dst = edges + N_EDGES;
    const float* W1 = (const float*)d_in[2];
    const float* b1 = (const float*)d_in[3];
    const float* W2 = (const float*)d_in[4];
    const float* b2 = (const float*)d_in[5];
    const float* fc1_w = (const float*)d_in[6];
    const float* fc1_b = (const float*)d_in[7];
    const float* fc2_w = (const float*)d_in[8];
    const float* fc2_b = (const float*)d_in[9];
    float* out = (float*)d_out;

    // workspace carve-up (all 256B-aligned)
    char* ws = (char*)d_ws;
    auto carve = [&](size_t bytes) {
        void* p = (void*)ws;
        ws += (bytes + 255) & ~(size_t)255;
        return p;
    };
    int* indeg = (int*)carve(N_NODES * 4);
    int* rowptr = (int*)carve((N_NODES + 1) * 4);
    int* cursor = (int*)carve(N_NODES * 4);
    float* dinv = (float*)carve(N_NODES * 4);
    int* col = (int*)carve(N_EDGES * 4);
    float* fc1t = (float*)carve(256 * 64 * 4);
    float* assign = (float*)carve(N_NODES * 2 * 4);
    float* gf = (float*)carve(516 * 4);        // gf[512] + newadj[4] contiguous
    float* newadj = gf + 512;
    float* a1pre = (float*)carve((size_t)N_NODES * 64 * 4);
    float* bufA = (float*)carve((size_t)N_NODES * 256 * 4);
    float* bufB = (float*)carve((size_t)N_NODES * 256 * 4);

    hipMemsetAsync(indeg, 0, N_NODES * 4, stream);
    hipMemsetAsync(gf, 0, 516 * 4, stream);

    // CSR build
    hist_kernel<<<N_EDGES / 256, 256, 0, stream>>>(dst, indeg);
    scan_kernel<<<1, 256, 0, stream>>>(indeg, rowptr, cursor, dinv);
    fill_kernel<<<N_EDGES / 256, 256, 0, stream>>>(src, dst, cursor, col);
    transpose_fc1<<<64, 256, 0, stream>>>(fc1_w, fc1t);

    // layer 1: y = (X @ W1) * dinv[row]; h1 = relu(agg(y) + b1)
    sgemm_rowscale<128, 128, 8, 8, 8>
        <<<dim3(H1 / 128, N_NODES / 128), 256, 0, stream>>>(
            features, W1, dinv, bufA, N_NODES, H1, F_IN);
    aggregate_kernel<<<N_NODES, 256, 0, stream>>>(bufA, rowptr, col, dinv, b1, bufB, 1);

    // layer 2: y = (h1 @ W2) * dinv[row]; h2 = agg(y) + b2
    sgemm_rowscale<128, 128, 8, 8, 8>
        <<<dim3(H2 / 128, N_NODES / 128), 256, 0, stream>>>(
            bufB, W2, dinv, bufA, N_NODES, H2, H1);
    aggregate_kernel<<<N_NODES, 256, 0, stream>>>(bufA, rowptr, col, dinv, b2, bufB, 0);
    // h2 = bufB

    // a1pre = h2 @ fc1t (no rowscale)
    sgemm_rowscale<128, 64, 8, 8, 4>
        <<<dim3(1, N_NODES / 128), 256, 0, stream>>>(
            bufB, fc1t, (const float*)nullptr, a1pre, N_NODES, 64, 256);

    // assignment = softmax(tanh(a1pre + b) @ fc2_w.T + fc2_b)
    assign_kernel<<<N_NODES, 64, 0, stream>>>(a1pre, fc1_b, fc2_w, fc2_b, assign);

    // pooled reductions
    group_feat_kernel<<<N_NODES / 256, 256, 0, stream>>>(bufB, assign, gf);
    newadj_kernel<<<N_EDGES / 256, 256, 0, stream>>>(src, dst, assign, newadj);
    finalize_kernel<<<1, 256, 0, stream>>>(gf, newadj, out);
}

// Round 2
// 465.640 us; speedup vs baseline: 1.8863x; 1.8863x over previous
//
#include <hip/hip_runtime.h>
#include <math.h>

#define N_NODES 16384
#define N_EDGES 524288
#define F_IN 128
#define H1 256
#define H2 256
#define D1 64
#define NEWADJ_BLOCKS 512

// ---------------- CSR build ----------------

__global__ void hist_kernel(const int* __restrict__ dst, int* __restrict__ indeg) {
    int e = blockIdx.x * 256 + threadIdx.x;
    if (e < N_EDGES) atomicAdd(&indeg[dst[e]], 1);
}

// single block, 256 threads; N=16384 -> 64 per thread
__global__ void scan_kernel(const int* __restrict__ indeg, int* __restrict__ rowptr,
                            int* __restrict__ cursor, float* __restrict__ dinv) {
    __shared__ int part[256];
    int t = threadIdx.x;
    int base = t * 64;
    int s = 0;
    for (int i = 0; i < 64; ++i) s += indeg[base + i];
    part[t] = s;
    __syncthreads();
    for (int off = 1; off < 256; off <<= 1) {
        int v = part[t];
        int add = (t >= off) ? part[t - off] : 0;
        __syncthreads();
        part[t] = v + add;
        __syncthreads();
    }
    int run = (t == 0) ? 0 : part[t - 1];
    for (int i = 0; i < 64; ++i) {
        int d = indeg[base + i];
        rowptr[base + i] = run;
        cursor[base + i] = run;
        dinv[base + i] = rsqrtf((float)(d + 1));   // +1 self loop; deg>=1 always
        run += d;
    }
    if (t == 255) rowptr[N_NODES] = run;
}

__global__ void fill_kernel(const int* __restrict__ src, const int* __restrict__ dst,
                            int* __restrict__ cursor, int* __restrict__ col) {
    int e = blockIdx.x * 256 + threadIdx.x;
    if (e < N_EDGES) {
        int d = dst[e];
        int p = atomicAdd(&cursor[d], 1);
        col[p] = src[e];
    }
}

// ---------------- SGEMM with row-scale epilogue ----------------
// C[i][j] = (sum_k A[i][k]*B[k][j]) * (rowscale ? rowscale[i] : 1)
template <int BM, int BN, int BK, int TM, int TN>
__global__ __launch_bounds__(256) void sgemm_rowscale(
    const float* __restrict__ A, const float* __restrict__ B,
    const float* __restrict__ rowscale, float* __restrict__ C,
    int M, int N, int K) {
    __shared__ float As[BK][BM];
    __shared__ float Bs[BK][BN];
    const int tid = threadIdx.x;
    const int tx = tid % (BN / TN);
    const int ty = tid / (BN / TN);
    const int row0 = blockIdx.y * BM;
    const int col0 = blockIdx.x * BN;
    float acc[TM][TN] = {};
    for (int k0 = 0; k0 < K; k0 += BK) {
        __syncthreads();
        #pragma unroll
        for (int i = tid; i < BM * BK; i += 256) {
            int r = i / BK, c = i % BK;
            As[c][r] = A[(size_t)(row0 + r) * K + k0 + c];
        }
        #pragma unroll
        for (int i = tid; i < BK * BN; i += 256) {
            int r = i / BN, c = i % BN;
            Bs[r][c] = B[(size_t)(k0 + r) * N + col0 + c];
        }
        __syncthreads();
        #pragma unroll
        for (int k = 0; k < BK; ++k) {
            float a[TM], b[TN];
            #pragma unroll
            for (int i = 0; i < TM; i += 4) {
                float4 v = *(const float4*)&As[k][ty * TM + i];
                a[i] = v.x; a[i + 1] = v.y; a[i + 2] = v.z; a[i + 3] = v.w;
            }
            #pragma unroll
            for (int j = 0; j < TN; j += 4) {
                float4 v = *(const float4*)&Bs[k][tx * TN + j];
                b[j] = v.x; b[j + 1] = v.y; b[j + 2] = v.z; b[j + 3] = v.w;
            }
            #pragma unroll
            for (int i = 0; i < TM; ++i)
                #pragma unroll
                for (int j = 0; j < TN; ++j)
                    acc[i][j] += a[i] * b[j];
        }
    }
    #pragma unroll
    for (int i = 0; i < TM; ++i) {
        float rs = rowscale ? rowscale[row0 + ty * TM + i] : 1.0f;
        #pragma unroll
        for (int j = 0; j < TN; j += 4) {
            float4 v;
            v.x = acc[i][j + 0] * rs;
            v.y = acc[i][j + 1] * rs;
            v.z = acc[i][j + 2] * rs;
            v.w = acc[i][j + 3] * rs;
            *(float4*)&C[(size_t)(row0 + ty * TM + i) * N + col0 + tx * TN + j] = v;
        }
    }
}

// ---------------- neighborhood aggregation ----------------
// out[d][f] = dinv[d] * (y[d][f] + sum_{s in nbr(d)} y[s][f]) + bias[f]; optional relu
__global__ __launch_bounds__(256) void aggregate_kernel(
    const float* __restrict__ y, const int* __restrict__ rowptr,
    const int* __restrict__ col, const float* __restrict__ dinv,
    const float* __restrict__ bias, float* __restrict__ out, int do_relu) {
    __shared__ int nb[256];
    int d = blockIdx.x;
    int f = threadIdx.x;
    int s0 = rowptr[d], s1 = rowptr[d + 1];
    float acc = y[(size_t)d * 256 + f];
    for (int base = s0; base < s1; base += 256) {
        int m = min(256, s1 - base);
        if (threadIdx.x < m) nb[threadIdx.x] = col[base + threadIdx.x];
        __syncthreads();
        for (int i = 0; i < m; ++i) acc += y[(size_t)nb[i] * 256 + f];
        __syncthreads();
    }
    float v = acc * dinv[d] + bias[f];
    if (do_relu) v = fmaxf(v, 0.0f);
    out[(size_t)d * 256 + f] = v;
}

// ---------------- small glue kernels ----------------

__global__ void transpose_fc1(const float* __restrict__ fc1_w, float* __restrict__ fc1t) {
    int i = blockIdx.x * 256 + threadIdx.x;   // 16384 = 256*64
    int k = i / 64, o = i % 64;
    fc1t[i] = fc1_w[o * 256 + k];             // fc1t[k][o] = fc1_w[o][k]
}

// tanh + 2-logit + softmax per node; one wave (64 threads) per node
__global__ __launch_bounds__(64) void assign_kernel(
    const float* __restrict__ a1pre, const float* __restrict__ fc1_b,
    const float* __restrict__ fc2_w, const float* __restrict__ fc2_b,
    float* __restrict__ assign) {
    int n = blockIdx.x, t = threadIdx.x;
    float a = tanhf(a1pre[(size_t)n * 64 + t] + fc1_b[t]);
    float p0 = a * fc2_w[t];
    float p1 = a * fc2_w[64 + t];
    #pragma unroll
    for (int off = 32; off; off >>= 1) {
        p0 += __shfl_down(p0, off);
        p1 += __shfl_down(p1, off);
    }
    if (t == 0) {
        p0 += fc2_b[0];
        p1 += fc2_b[1];
        float m = fmaxf(p0, p1);
        float e0 = expf(p0 - m), e1 = expf(p1 - m);
        float inv = 1.0f / (e0 + e1);
        assign[n * 2 + 0] = e0 * inv;
        assign[n * 2 + 1] = e1 * inv;
    }
}

// gf[k][f] = sum_n assign[n][k] * h2[n][f];  64 blocks of 256 nodes each
__global__ __launch_bounds__(256) void group_feat_kernel(
    const float* __restrict__ h2, const float* __restrict__ assign,
    float* __restrict__ gf) {
    __shared__ float as0[256], as1[256];
    int f = threadIdx.x;
    int n0 = blockIdx.x * 256;
    as0[f] = assign[(n0 + f) * 2 + 0];
    as1[f] = assign[(n0 + f) * 2 + 1];
    __syncthreads();
    float acc0 = 0.f, acc1 = 0.f;
    for (int i = 0; i < 256; ++i) {
        float h = h2[(size_t)(n0 + i) * 256 + f];
        acc0 += as0[i] * h;
        acc1 += as1[i] * h;
    }
    atomicAdd(&gf[f], acc0);
    atomicAdd(&gf[256 + f], acc1);
}

// new_adj[k][l] = sum_e assign[src_e][k]*assign[dst_e][l]
// Two-stage: per-block partials (NO contended atomics), reduced in finalize.
__global__ __launch_bounds__(256) void newadj_kernel(
    const int* __restrict__ src, const int* __restrict__ dst,
    const float* __restrict__ assign, float* __restrict__ part) {
    __shared__ float red[4][4];   // [wave][component]
    float a00 = 0.f, a01 = 0.f, a10 = 0.f, a11 = 0.f;
    for (int e = blockIdx.x * 256 + threadIdx.x; e < N_EDGES;
         e += NEWADJ_BLOCKS * 256) {
        int s = src[e], d = dst[e];
        float s0 = assign[s * 2], s1 = assign[s * 2 + 1];
        float d0 = assign[d * 2], d1 = assign[d * 2 + 1];
        a00 += s0 * d0; a01 += s0 * d1; a10 += s1 * d0; a11 += s1 * d1;
    }
    #pragma unroll
    for (int off = 32; off; off >>= 1) {
        a00 += __shfl_down(a00, off);
        a01 += __shfl_down(a01, off);
        a10 += __shfl_down(a10, off);
        a11 += __shfl_down(a11, off);
    }
    int wave = threadIdx.x >> 6;
    if ((threadIdx.x & 63) == 0) {
        red[wave][0] = a00; red[wave][1] = a01;
        red[wave][2] = a10; red[wave][3] = a11;
    }
    __syncthreads();
    if (threadIdx.x < 4) {
        float v = red[0][threadIdx.x] + red[1][threadIdx.x] +
                  red[2][threadIdx.x] + red[3][threadIdx.x];
        part[blockIdx.x * 4 + threadIdx.x] = v;
    }
}

__global__ __launch_bounds__(256) void finalize_kernel(
    const float* __restrict__ gf, const float* __restrict__ part,
    float* __restrict__ out) {
    __shared__ float na[4];
    int t = threadIdx.x;
    // reduce newadj partials: wave w handles component w
    int wave = t >> 6, lane = t & 63;
    float acc = 0.f;
    for (int i = lane; i < NEWADJ_BLOCKS; i += 64) acc += part[i * 4 + wave];
    #pragma unroll
    for (int off = 32; off; off >>= 1) acc += __shfl_down(acc, off);
    if (lane == 0) na[wave] = acc;
    __syncthreads();
    float g0 = gf[t], g1 = gf[256 + t];
    out[t] = 0.5f * (g0 + g1);                                   // graph_embedding
    out[256 + t] = fminf(fmaxf(g0, -100.f), 100.f);              // positive
    out[512 + t] = fminf(fmaxf(g1, -100.f), 100.f);              // negative
    if (t == 0) {
        float n00 = na[0], n01 = na[1], n10 = na[2], n11 = na[3];
        float den0 = fmaxf(fabsf(n00) + fabsf(n01), 1e-12f);
        float den1 = fmaxf(fabsf(n10) + fabsf(n11), 1e-12f);
        float x0 = n00 / den0 - 1.0f;
        float x1 = n11 / den1 - 1.0f;
        out[768] = 0.5f * (x0 * x0 + x1 * x1);                   // pos_penalty
    }
}

// ---------------- launch ----------------

extern "C" void kernel_launch(void* const* d_in, const int* in_sizes, int n_in,
                              void* d_out, int out_size, void* d_ws, size_t ws_size,
                              hipStream_t stream) {
    const float* features = (const float*)d_in[0];
    const int* edges = (const int*)d_in[1];
    const int* src = edges;
    const int* dst = edges + N_EDGES;
    const float* W1 = (const float*)d_in[2];
    const float* b1 = (const float*)d_in[3];
    const float* W2 = (const float*)d_in[4];
    const float* b2 = (const float*)d_in[5];
    const float* fc1_w = (const float*)d_in[6];
    const float* fc1_b = (const float*)d_in[7];
    const float* fc2_w = (const float*)d_in[8];
    const float* fc2_b = (const float*)d_in[9];
    float* out = (float*)d_out;

    // workspace carve-up (all 256B-aligned)
    char* ws = (char*)d_ws;
    auto carve = [&](size_t bytes) {
        void* p = (void*)ws;
        ws += (bytes + 255) & ~(size_t)255;
        return p;
    };
    int* indeg = (int*)carve(N_NODES * 4);
    int* rowptr = (int*)carve((N_NODES + 1) * 4);
    int* cursor = (int*)carve(N_NODES * 4);
    float* dinv = (float*)carve(N_NODES * 4);
    int* col = (int*)carve(N_EDGES * 4);
    float* fc1t = (float*)carve(256 * 64 * 4);
    float* assign = (float*)carve(N_NODES * 2 * 4);
    float* gf = (float*)carve(512 * 4);
    float* napart = (float*)carve(NEWADJ_BLOCKS * 4 * 4);
    float* a1pre = (float*)carve((size_t)N_NODES * 64 * 4);
    float* bufA = (float*)carve((size_t)N_NODES * 256 * 4);
    float* bufB = (float*)carve((size_t)N_NODES * 256 * 4);

    hipMemsetAsync(indeg, 0, N_NODES * 4, stream);
    hipMemsetAsync(gf, 0, 512 * 4, stream);

    // CSR build
    hist_kernel<<<N_EDGES / 256, 256, 0, stream>>>(dst, indeg);
    scan_kernel<<<1, 256, 0, stream>>>(indeg, rowptr, cursor, dinv);
    fill_kernel<<<N_EDGES / 256, 256, 0, stream>>>(src, dst, cursor, col);
    transpose_fc1<<<64, 256, 0, stream>>>(fc1_w, fc1t);

    // layer 1: y = (X @ W1) * dinv[row]; h1 = relu(agg(y) + b1)
    sgemm_rowscale<128, 128, 8, 8, 8>
        <<<dim3(H1 / 128, N_NODES / 128), 256, 0, stream>>>(
            features, W1, dinv, bufA, N_NODES, H1, F_IN);
    aggregate_kernel<<<N_NODES, 256, 0, stream>>>(bufA, rowptr, col, dinv, b1, bufB, 1);

    // layer 2: y = (h1 @ W2) * dinv[row]; h2 = agg(y) + b2
    sgemm_rowscale<128, 128, 8, 8, 8>
        <<<dim3(H2 / 128, N_NODES / 128), 256, 0, stream>>>(
            bufB, W2, dinv, bufA, N_NODES, H2, H1);
    aggregate_kernel<<<N_NODES, 256, 0, stream>>>(bufA, rowptr, col, dinv, b2, bufB, 0);
    // h2 = bufB

    // a1pre = h2 @ fc1t (no rowscale)
    sgemm_rowscale<128, 64, 8, 8, 4>
        <<<dim3(1, N_NODES / 128), 256, 0, stream>>>(
            bufB, fc1t, (const float*)nullptr, a1pre, N_NODES, 64, 256);

    // assignment = softmax(tanh(a1pre + b) @ fc2_w.T + fc2_b)
    assign_kernel<<<N_NODES, 64, 0, stream>>>(a1pre, fc1_b, fc2_w, fc2_b, assign);

    // pooled reductions
    group_feat_kernel<<<N_NODES / 256, 256, 0, stream>>>(bufB, assign, gf);
    newadj_kernel<<<NEWADJ_BLOCKS, 256, 0, stream>>>(src, dst, assign, napart);
    finalize_kernel<<<1, 256, 0, stream>>>(gf, napart, out);
}

// Round 3
// 268.466 us; speedup vs baseline: 3.2717x; 1.7344x over previous
//
#include <hip/hip_runtime.h>
#include <hip/hip_bf16.h>
#include <math.h>

#define N_NODES 16384
#define N_EDGES 524288
#define F_IN 128
#define H1 256
#define H2 256
#define D1 64
#define NEWADJ_BLOCKS 512

typedef __attribute__((ext_vector_type(8))) short short8;
typedef __attribute__((ext_vector_type(4))) float floatx4;
typedef unsigned short ushort_t;
typedef unsigned int uint_t;

__device__ inline float bf2f(ushort_t u) {
    union { uint_t i; float f; } v;
    v.i = ((uint_t)u) << 16;
    return v.f;
}
__device__ inline ushort_t f2bs(float x) {
    __hip_bfloat16 h = __float2bfloat16(x);   // RNE
    return *reinterpret_cast<ushort_t*>(&h);
}

// ---------------- CSR build ----------------

__global__ void hist_kernel(const int* __restrict__ dst, int* __restrict__ indeg) {
    int e = blockIdx.x * 256 + threadIdx.x;
    if (e < N_EDGES) atomicAdd(&indeg[dst[e]], 1);
}

__global__ void scan_kernel(const int* __restrict__ indeg, int* __restrict__ rowptr,
                            int* __restrict__ cursor, float* __restrict__ dinv) {
    __shared__ int part[256];
    int t = threadIdx.x;
    int base = t * 64;
    int s = 0;
    for (int i = 0; i < 64; ++i) s += indeg[base + i];
    part[t] = s;
    __syncthreads();
    for (int off = 1; off < 256; off <<= 1) {
        int v = part[t];
        int add = (t >= off) ? part[t - off] : 0;
        __syncthreads();
        part[t] = v + add;
        __syncthreads();
    }
    int run = (t == 0) ? 0 : part[t - 1];
    for (int i = 0; i < 64; ++i) {
        int d = indeg[base + i];
        rowptr[base + i] = run;
        cursor[base + i] = run;
        dinv[base + i] = rsqrtf((float)(d + 1));   // +1 self loop
        run += d;
    }
    if (t == 255) rowptr[N_NODES] = run;
}

__global__ void fill_kernel(const int* __restrict__ src, const int* __restrict__ dst,
                            int* __restrict__ cursor, int* __restrict__ col) {
    int e = blockIdx.x * 256 + threadIdx.x;
    if (e < N_EDGES) {
        int d = dst[e];
        int p = atomicAdd(&cursor[d], 1);
        col[p] = src[e];
    }
}

// ---------------- prep: fp32 -> bf16 converts + weight transposes ----------------
// blocks [0,2048): features convert (4 elems/thread)
// blocks [2048,2176): W1t[n][k] = W1[k][n]   (256x128)
// blocks [2176,2432): W2t[n][k] = W2[k][n]   (256x256)
// blocks [2432,2496): fc1bf = convert(fc1_w) (64x256, already [out][k])
__global__ __launch_bounds__(256) void prep_kernel(
    const float* __restrict__ features, const float* __restrict__ W1,
    const float* __restrict__ W2, const float* __restrict__ fc1_w,
    ushort_t* __restrict__ featbf, ushort_t* __restrict__ W1t,
    ushort_t* __restrict__ W2t, ushort_t* __restrict__ fc1bf) {
    int b = blockIdx.x, t = threadIdx.x;
    if (b < 2048) {
        int idx = (b * 256 + t) * 4;
        float4 v = *(const float4*)&features[idx];
        uint_t lo = (uint_t)f2bs(v.x) | ((uint_t)f2bs(v.y) << 16);
        uint_t hi = (uint_t)f2bs(v.z) | ((uint_t)f2bs(v.w) << 16);
        uint2 p; p.x = lo; p.y = hi;
        *(uint2*)&featbf[idx] = p;
    } else if (b < 2176) {
        int idx = (b - 2048) * 256 + t;      // 0..32767
        int n = idx >> 7, k = idx & 127;
        W1t[idx] = f2bs(W1[k * 256 + n]);
    } else if (b < 2432) {
        int idx = (b - 2176) * 256 + t;      // 0..65535
        int n = idx >> 8, k = idx & 255;
        W2t[idx] = f2bs(W2[k * 256 + n]);
    } else {
        int idx = (b - 2432) * 256 + t;      // 0..16383
        fc1bf[idx] = f2bs(fc1_w[idx]);
    }
}

// ---------------- bf16 MFMA GEMM ----------------
// A row-major [M][K] bf16, Bt [N][K] bf16 (B transposed), epilogue:
//   C[i][j] = acc * (ROWSCALE ? rowscale[i] : 1)  -> bf16 or fp32
// 256 threads = 4 waves in 2x2; wave tile (BM/2)x(BN/2); BK=32.
template <int BM, int BN, bool OUT_BF16, bool ROWSCALE>
__global__ __launch_bounds__(256) void gemm_bf16(
    const ushort_t* __restrict__ A, const ushort_t* __restrict__ Bt,
    const float* __restrict__ rowscale, void* __restrict__ Cv,
    int K, int N) {
    constexpr int BK = 32;
    constexpr int LDA = BK + 8;              // pad: 80B rows -> 2-way max
    constexpr int RM = BM / 2 / 16;
    constexpr int RN = BN / 2 / 16;
    __shared__ ushort_t As[BM * LDA];
    __shared__ ushort_t Bs[BN * LDA];
    const int tid = threadIdx.x;
    const int lane = tid & 63;
    const int wave = tid >> 6;
    const int m = lane & 15;
    const int quad = lane >> 4;
    const int row0 = blockIdx.y * BM;
    const int col0 = blockIdx.x * BN;
    const int wrow0 = (wave >> 1) * (BM / 2);
    const int wcol0 = (wave & 1) * (BN / 2);

    floatx4 acc[RM][RN];
    const floatx4 zero4 = {0.f, 0.f, 0.f, 0.f};
    #pragma unroll
    for (int i = 0; i < RM; ++i)
        #pragma unroll
        for (int j = 0; j < RN; ++j) acc[i][j] = zero4;

    for (int k0 = 0; k0 < K; k0 += BK) {
        __syncthreads();
        #pragma unroll
        for (int i = tid; i < BM * BK / 8; i += 256) {
            int e = i * 8;
            int r = e / BK, c = e % BK;
            *(uint4*)&As[r * LDA + c] =
                *(const uint4*)&A[(size_t)(row0 + r) * K + k0 + c];
        }
        #pragma unroll
        for (int i = tid; i < BN * BK / 8; i += 256) {
            int e = i * 8;
            int r = e / BK, c = e % BK;
            *(uint4*)&Bs[r * LDA + c] =
                *(const uint4*)&Bt[(size_t)(col0 + r) * K + k0 + c];
        }
        __syncthreads();
        short8 a[RM], b[RN];
        #pragma unroll
        for (int i = 0; i < RM; ++i)
            a[i] = *(const short8*)&As[(wrow0 + i * 16 + m) * LDA + quad * 8];
        #pragma unroll
        for (int j = 0; j < RN; ++j)
            b[j] = *(const short8*)&Bs[(wcol0 + j * 16 + m) * LDA + quad * 8];
        #pragma unroll
        for (int i = 0; i < RM; ++i)
            #pragma unroll
            for (int j = 0; j < RN; ++j)
                acc[i][j] = __builtin_amdgcn_mfma_f32_16x16x32_bf16(
                    a[i], b[j], acc[i][j], 0, 0, 0);
    }

    ushort_t* Cb = (ushort_t*)Cv;
    float* Cf = (float*)Cv;
    #pragma unroll
    for (int i = 0; i < RM; ++i) {
        int rbase = row0 + wrow0 + i * 16 + quad * 4;
        float rs4[4];
        #pragma unroll
        for (int r = 0; r < 4; ++r)
            rs4[r] = ROWSCALE ? rowscale[rbase + r] : 1.0f;
        #pragma unroll
        for (int j = 0; j < RN; ++j) {
            int cg = col0 + wcol0 + j * 16 + m;
            #pragma unroll
            for (int r = 0; r < 4; ++r) {
                float v = acc[i][j][r] * rs4[r];
                if (OUT_BF16) Cb[(size_t)(rbase + r) * N + cg] = f2bs(v);
                else          Cf[(size_t)(rbase + r) * N + cg] = v;
            }
        }
    }
}

// ---------------- bf16 neighborhood aggregation ----------------
// out[d][f] = bf16( dinv[d] * (y[d][f] + sum_nbr y[s][f]) + bias[f] ), opt relu
// 128 threads/node; thread t handles features {2t, 2t+1} as one uint.
__global__ __launch_bounds__(128) void aggregate_bf16(
    const ushort_t* __restrict__ y, const int* __restrict__ rowptr,
    const int* __restrict__ col, const float* __restrict__ dinv,
    const float* __restrict__ bias, ushort_t* __restrict__ out, int do_relu) {
    __shared__ int nb[128];
    int d = blockIdx.x;
    int t = threadIdx.x;
    int s0 = rowptr[d], s1 = rowptr[d + 1];
    uint_t self = *(const uint_t*)&y[(size_t)d * 256 + 2 * t];
    float acc0 = bf2f((ushort_t)(self & 0xffff));
    float acc1 = bf2f((ushort_t)(self >> 16));
    for (int base = s0; base < s1; base += 128) {
        int mcnt = min(128, s1 - base);
        if (t < mcnt) nb[t] = col[base + t];
        __syncthreads();
        for (int i = 0; i < mcnt; ++i) {
            uint_t v = *(const uint_t*)&y[(size_t)nb[i] * 256 + 2 * t];
            acc0 += bf2f((ushort_t)(v & 0xffff));
            acc1 += bf2f((ushort_t)(v >> 16));
        }
        __syncthreads();
    }
    float di = dinv[d];
    float v0 = acc0 * di + bias[2 * t];
    float v1 = acc1 * di + bias[2 * t + 1];
    if (do_relu) { v0 = fmaxf(v0, 0.f); v1 = fmaxf(v1, 0.f); }
    uint_t packed = (uint_t)f2bs(v0) | ((uint_t)f2bs(v1) << 16);
    *(uint_t*)&out[(size_t)d * 256 + 2 * t] = packed;
}

// ---------------- assignment MLP tail ----------------
__global__ __launch_bounds__(64) void assign_kernel(
    const float* __restrict__ a1pre, const float* __restrict__ fc1_b,
    const float* __restrict__ fc2_w, const float* __restrict__ fc2_b,
    float* __restrict__ assign) {
    int n = blockIdx.x, t = threadIdx.x;
    float a = tanhf(a1pre[(size_t)n * 64 + t] + fc1_b[t]);
    float p0 = a * fc2_w[t];
    float p1 = a * fc2_w[64 + t];
    #pragma unroll
    for (int off = 32; off; off >>= 1) {
        p0 += __shfl_down(p0, off);
        p1 += __shfl_down(p1, off);
    }
    if (t == 0) {
        p0 += fc2_b[0];
        p1 += fc2_b[1];
        float mx = fmaxf(p0, p1);
        float e0 = expf(p0 - mx), e1 = expf(p1 - mx);
        float inv = 1.0f / (e0 + e1);
        assign[n * 2 + 0] = e0 * inv;
        assign[n * 2 + 1] = e1 * inv;
    }
}

// gf[k][f] = sum_n assign[n][k] * h2[n][f]; h2 in bf16
__global__ __launch_bounds__(256) void group_feat_kernel(
    const ushort_t* __restrict__ h2, const float* __restrict__ assign,
    float* __restrict__ gf) {
    __shared__ float as0[256], as1[256];
    int f = threadIdx.x;
    int n0 = blockIdx.x * 256;
    as0[f] = assign[(n0 + f) * 2 + 0];
    as1[f] = assign[(n0 + f) * 2 + 1];
    __syncthreads();
    float acc0 = 0.f, acc1 = 0.f;
    for (int i = 0; i < 256; ++i) {
        float h = bf2f(h2[(size_t)(n0 + i) * 256 + f]);
        acc0 += as0[i] * h;
        acc1 += as1[i] * h;
    }
    atomicAdd(&gf[f], acc0);
    atomicAdd(&gf[256 + f], acc1);
}

// new_adj partials, no contended atomics
__global__ __launch_bounds__(256) void newadj_kernel(
    const int* __restrict__ src, const int* __restrict__ dst,
    const float* __restrict__ assign, float* __restrict__ part) {
    __shared__ float red[4][4];
    float a00 = 0.f, a01 = 0.f, a10 = 0.f, a11 = 0.f;
    for (int e = blockIdx.x * 256 + threadIdx.x; e < N_EDGES;
         e += NEWADJ_BLOCKS * 256) {
        int s = src[e], d = dst[e];
        float s0 = assign[s * 2], s1 = assign[s * 2 + 1];
        float d0 = assign[d * 2], d1 = assign[d * 2 + 1];
        a00 += s0 * d0; a01 += s0 * d1; a10 += s1 * d0; a11 += s1 * d1;
    }
    #pragma unroll
    for (int off = 32; off; off >>= 1) {
        a00 += __shfl_down(a00, off);
        a01 += __shfl_down(a01, off);
        a10 += __shfl_down(a10, off);
        a11 += __shfl_down(a11, off);
    }
    int wave = threadIdx.x >> 6;
    if ((threadIdx.x & 63) == 0) {
        red[wave][0] = a00; red[wave][1] = a01;
        red[wave][2] = a10; red[wave][3] = a11;
    }
    __syncthreads();
    if (threadIdx.x < 4) {
        float v = red[0][threadIdx.x] + red[1][threadIdx.x] +
                  red[2][threadIdx.x] + red[3][threadIdx.x];
        part[blockIdx.x * 4 + threadIdx.x] = v;
    }
}

__global__ __launch_bounds__(256) void finalize_kernel(
    const float* __restrict__ gf, const float* __restrict__ part,
    float* __restrict__ out) {
    __shared__ float na[4];
    int t = threadIdx.x;
    int wave = t >> 6, lane = t & 63;
    float acc = 0.f;
    for (int i = lane; i < NEWADJ_BLOCKS; i += 64) acc += part[i * 4 + wave];
    #pragma unroll
    for (int off = 32; off; off >>= 1) acc += __shfl_down(acc, off);
    if (lane == 0) na[wave] = acc;
    __syncthreads();
    float g0 = gf[t], g1 = gf[256 + t];
    out[t] = 0.5f * (g0 + g1);
    out[256 + t] = fminf(fmaxf(g0, -100.f), 100.f);
    out[512 + t] = fminf(fmaxf(g1, -100.f), 100.f);
    if (t == 0) {
        float n00 = na[0], n01 = na[1], n10 = na[2], n11 = na[3];
        float den0 = fmaxf(fabsf(n00) + fabsf(n01), 1e-12f);
        float den1 = fmaxf(fabsf(n10) + fabsf(n11), 1e-12f);
        float x0 = n00 / den0 - 1.0f;
        float x1 = n11 / den1 - 1.0f;
        out[768] = 0.5f * (x0 * x0 + x1 * x1);
    }
}

// ---------------- launch ----------------

extern "C" void kernel_launch(void* const* d_in, const int* in_sizes, int n_in,
                              void* d_out, int out_size, void* d_ws, size_t ws_size,
                              hipStream_t stream) {
    const float* features = (const float*)d_in[0];
    const int* edges = (const int*)d_in[1];
    const int* src = edges;
    const int* dst = edges + N_EDGES;
    const float* W1 = (const float*)d_in[2];
    const float* b1 = (const float*)d_in[3];
    const float* W2 = (const float*)d_in[4];
    const float* b2 = (const float*)d_in[5];
    const float* fc1_w = (const float*)d_in[6];
    const float* fc1_b = (const float*)d_in[7];
    const float* fc2_w = (const float*)d_in[8];
    const float* fc2_b = (const float*)d_in[9];
    float* out = (float*)d_out;

    char* ws = (char*)d_ws;
    auto carve = [&](size_t bytes) {
        void* p = (void*)ws;
        ws += (bytes + 255) & ~(size_t)255;
        return p;
    };
    int* indeg = (int*)carve(N_NODES * 4);
    int* rowptr = (int*)carve((N_NODES + 1) * 4);
    int* cursor = (int*)carve(N_NODES * 4);
    float* dinv = (float*)carve(N_NODES * 4);
    int* col = (int*)carve(N_EDGES * 4);
    float* assign = (float*)carve(N_NODES * 2 * 4);
    float* gf = (float*)carve(512 * 4);
    float* napart = (float*)carve(NEWADJ_BLOCKS * 4 * 4);
    float* a1pre = (float*)carve((size_t)N_NODES * 64 * 4);
    ushort_t* featbf = (ushort_t*)carve((size_t)N_NODES * F_IN * 2);
    ushort_t* W1t = (ushort_t*)carve(256 * 128 * 2);
    ushort_t* W2t = (ushort_t*)carve(256 * 256 * 2);
    ushort_t* fc1bf = (ushort_t*)carve(64 * 256 * 2);
    ushort_t* bufY = (ushort_t*)carve((size_t)N_NODES * 256 * 2);
    ushort_t* bufH = (ushort_t*)carve((size_t)N_NODES * 256 * 2);

    hipMemsetAsync(indeg, 0, N_NODES * 4, stream);
    hipMemsetAsync(gf, 0, 512 * 4, stream);

    // CSR build + converts
    hist_kernel<<<N_EDGES / 256, 256, 0, stream>>>(dst, indeg);
    scan_kernel<<<1, 256, 0, stream>>>(indeg, rowptr, cursor, dinv);
    fill_kernel<<<N_EDGES / 256, 256, 0, stream>>>(src, dst, cursor, col);
    prep_kernel<<<2496, 256, 0, stream>>>(features, W1, W2, fc1_w,
                                          featbf, W1t, W2t, fc1bf);

    // layer 1: y = (X @ W1) * dinv; h1 = relu(agg(y) + b1)
    gemm_bf16<128, 128, true, true>
        <<<dim3(H1 / 128, N_NODES / 128), 256, 0, stream>>>(
            featbf, W1t, dinv, bufY, F_IN, H1);
    aggregate_bf16<<<N_NODES, 128, 0, stream>>>(bufY, rowptr, col, dinv, b1, bufH, 1);

    // layer 2: y = (h1 @ W2) * dinv; h2 = agg(y) + b2
    gemm_bf16<128, 128, true, true>
        <<<dim3(H2 / 128, N_NODES / 128), 256, 0, stream>>>(
            bufH, W2t, dinv, bufY, H1, H2);
    aggregate_bf16<<<N_NODES, 128, 0, stream>>>(bufY, rowptr, col, dinv, b2, bufH, 0);
    // h2 = bufH (bf16)

    // a1pre = h2 @ fc1_w.T   (fc1bf already [out][k] layout)
    gemm_bf16<128, 64, false, false>
        <<<dim3(1, N_NODES / 128), 256, 0, stream>>>(
            bufH, fc1bf, (const float*)nullptr, a1pre, H2, D1);

    assign_kernel<<<N_NODES, 64, 0, stream>>>(a1pre, fc1_b, fc2_w, fc2_b, assign);

    group_feat_kernel<<<N_NODES / 256, 256, 0, stream>>>(bufH, assign, gf);
    newadj_kernel<<<NEWADJ_BLOCKS, 256, 0, stream>>>(src, dst, assign, napart);
    finalize_kernel<<<1, 256, 0, stream>>>(gf, napart, out);
}